// Round 2
// baseline (73.697 us; speedup 1.0000x reference)
//
#include <hip/hip_runtime.h>
#include <hip/hip_bf16.h>

#define BLOCK 256
#define NCHUNKS 16          // N split for parallelism: 64 x 16 = 1024 blocks, 16 waves/CU
#define LOG2E 1.44269504088896340736f

// v(p_m) = sum_n exp(-|p_m - g_n|^2) * c_n   (SIGMA = 1)
// exp(-|p-g|^2) = exp(-|p|^2) * [exp(-|g|^2)] * exp2(2*log2e * p.g)
// Prep kernel folds exp(-|g|^2) into controls and 2*log2e into g, writing a
// float4 table (gx', gy', c0', c1') to d_ws. Main kernel's inner loop reads the
// table with wave-UNIFORM addresses (scalarizes to s_load / broadcast L1 hit),
// so per (wave, j) it is just: v_mul, v_fma (dot), v_exp_f32, v_fma, v_fma.
// Round 1 was LDS-throughput-bound (ds_read_b128 ~12 cyc x 16 waves/CU x 256 j
// = ~20 us); this removes LDS from the loop entirely.

__global__ void __launch_bounds__(BLOCK)
prep_kernel(const float* __restrict__ gd, const float* __restrict__ controls,
            float4* __restrict__ table, int N) {
    int n = blockIdx.x * BLOCK + threadIdx.x;
    if (n < N) {
        float2 g = ((const float2*)gd)[n];
        float2 c = ((const float2*)controls)[n];
        float  e = __expf(-(g.x * g.x + g.y * g.y));
        table[n] = make_float4(g.x * (2.0f * LOG2E), g.y * (2.0f * LOG2E),
                               c.x * e, c.y * e);
    }
}

__global__ void __launch_bounds__(BLOCK)
translations_main(const float4* __restrict__ table,
                  const float* __restrict__ points,
                  float* __restrict__ out,
                  int chunk_len, int M) {
    const int m = blockIdx.x * BLOCK + threadIdx.x;
    const float4* __restrict__ t = table + (size_t)blockIdx.y * chunk_len;

    if (m >= M) return;
    const float2 p = ((const float2*)points)[m];

    float acc0 = 0.f, acc1 = 0.f;
#pragma unroll 8
    for (int j = 0; j < chunk_len; ++j) {
        float4 g = t[j];                                  // uniform addr -> SMEM/L1 broadcast
        float  e = __builtin_amdgcn_exp2f(fmaf(g.x, p.x, g.y * p.y));
        acc0 = fmaf(e, g.z, acc0);
        acc1 = fmaf(e, g.w, acc1);
    }

    const float s = __expf(-(p.x * p.x + p.y * p.y));
    atomicAdd(&out[2 * m],     acc0 * s);
    atomicAdd(&out[2 * m + 1], acc1 * s);
}

extern "C" void kernel_launch(void* const* d_in, const int* in_sizes, int n_in,
                              void* d_out, int out_size, void* d_ws, size_t ws_size,
                              hipStream_t stream) {
    const float* gd       = (const float*)d_in[0];  // [N*2]
    const float* controls = (const float*)d_in[1];  // [N*2]
    const float* points   = (const float*)d_in[2];  // [M,2]
    float* out = (float*)d_out;                     // [M,2] fp32
    float4* table = (float4*)d_ws;                  // [N] folded (gx', gy', c0', c1')

    const int N = in_sizes[0] / 2;
    const int M = in_sizes[2] / 2;

    // d_out is poisoned with 0xAA before every timed launch; atomics need zeros.
    hipMemsetAsync(d_out, 0, (size_t)out_size * sizeof(float), stream);

    prep_kernel<<<(N + BLOCK - 1) / BLOCK, BLOCK, 0, stream>>>(gd, controls, table, N);

    const int chunk_len = N / NCHUNKS;              // 4096/16 = 256, exact
    dim3 grid((M + BLOCK - 1) / BLOCK, NCHUNKS);
    translations_main<<<grid, dim3(BLOCK), 0, stream>>>(table, points, out, chunk_len, M);
}

// Round 3
// 72.695 us; speedup vs baseline: 1.0138x; 1.0138x over previous
//
#include <hip/hip_runtime.h>
#include <hip/hip_bf16.h>

#define BLOCK 256
#define NCHUNKS 16          // grid = 64 x 16 = 1024 blocks -> 16 waves/CU
#define LOG2E 1.44269504088896340736f

using v2f = __attribute__((ext_vector_type(2))) float;

// v(p_m) = sum_n exp(-|p_m - g_n|^2) * c_n   (SIGMA = 1)
// exp(-|p-g|^2) = exp(-|p|^2) * [exp(-|g|^2)] * exp2(2*log2e * p.g)
// R1/R2 post-mortem: load path (LDS vs global) is irrelevant — memory issues on
// a separate port. Floor is VALU+trans issue: 4 VALU + 1 v_exp per (m,n) = 16
// cyc/j. R3: packed fp32 (v_pk_fma_f32) processes 2 n per iter -> per 2j:
// pk_mul + pk_fma (dot) + 2x v_exp + 2x pk_fma (acc) = 24 cyc/2j = 12 cyc/j.
// Table layout pair-SoA: tab[2k]=(gx0,gx1,gy0,gy1), tab[2k+1]=(c00,c01,c10,c11)
// so packed operands are consecutive VGPRs straight from global_load_dwordx4.

__global__ void __launch_bounds__(BLOCK)
prep_kernel(const float* __restrict__ gd, const float* __restrict__ controls,
            float4* __restrict__ tab, int Npairs) {
    int k = blockIdx.x * BLOCK + threadIdx.x;
    if (k < Npairs) {
        float2 g0 = ((const float2*)gd)[2 * k];
        float2 g1 = ((const float2*)gd)[2 * k + 1];
        float2 c0 = ((const float2*)controls)[2 * k];
        float2 c1 = ((const float2*)controls)[2 * k + 1];
        float  e0 = __expf(-(g0.x * g0.x + g0.y * g0.y));
        float  e1 = __expf(-(g1.x * g1.x + g1.y * g1.y));
        const float L2 = 2.0f * LOG2E;
        tab[2 * k]     = make_float4(g0.x * L2, g1.x * L2, g0.y * L2, g1.y * L2);
        tab[2 * k + 1] = make_float4(c0.x * e0, c1.x * e1, c0.y * e0, c1.y * e1);
    }
}

__global__ void __launch_bounds__(BLOCK)
translations_main(const float4* __restrict__ tab,
                  const float* __restrict__ points,
                  float* __restrict__ out,
                  int pairs_per_chunk, int M) {
    const int m = blockIdx.x * BLOCK + threadIdx.x;
    const float4* __restrict__ t = tab + (size_t)blockIdx.y * pairs_per_chunk * 2;

    if (m >= M) return;
    const float2 p = ((const float2*)points)[m];
    const v2f px = {p.x, p.x};
    const v2f py = {p.y, p.y};

    v2f acc0 = {0.f, 0.f};
    v2f acc1 = {0.f, 0.f};
#pragma unroll 4
    for (int k = 0; k < pairs_per_chunk; ++k) {
        float4 A = t[2 * k];                    // (gx0, gx1, gy0, gy1) * 2*log2e
        float4 B = t[2 * k + 1];                // (c00, c01, c10, c11) * exp(-|g|^2)
        v2f gx = {A.x, A.y}, gy = {A.z, A.w};
        v2f c0 = {B.x, B.y}, c1 = {B.z, B.w};
        v2f d  = __builtin_elementwise_fma(gy, py, gx * px);  // v_pk_mul + v_pk_fma
        v2f e  = { __builtin_amdgcn_exp2f(d.x),
                   __builtin_amdgcn_exp2f(d.y) };             // 2x v_exp_f32
        acc0 = __builtin_elementwise_fma(e, c0, acc0);        // v_pk_fma
        acc1 = __builtin_elementwise_fma(e, c1, acc1);        // v_pk_fma
    }

    const float s = __expf(-(p.x * p.x + p.y * p.y));
    atomicAdd(&out[2 * m],     (acc0.x + acc0.y) * s);
    atomicAdd(&out[2 * m + 1], (acc1.x + acc1.y) * s);
}

extern "C" void kernel_launch(void* const* d_in, const int* in_sizes, int n_in,
                              void* d_out, int out_size, void* d_ws, size_t ws_size,
                              hipStream_t stream) {
    const float* gd       = (const float*)d_in[0];  // [N*2]
    const float* controls = (const float*)d_in[1];  // [N*2]
    const float* points   = (const float*)d_in[2];  // [M,2]
    float* out = (float*)d_out;                     // [M,2] fp32
    float4* tab = (float4*)d_ws;                    // [N/2 pairs][2] float4

    const int N = in_sizes[0] / 2;
    const int M = in_sizes[2] / 2;
    const int Npairs = N / 2;                       // 2048 (N=4096 even)

    // d_out is poisoned with 0xAA before every timed launch; atomics need zeros.
    hipMemsetAsync(d_out, 0, (size_t)out_size * sizeof(float), stream);

    prep_kernel<<<(Npairs + BLOCK - 1) / BLOCK, BLOCK, 0, stream>>>(gd, controls, tab, Npairs);

    const int pairs_per_chunk = Npairs / NCHUNKS;   // 2048/16 = 128, exact
    dim3 grid((M + BLOCK - 1) / BLOCK, NCHUNKS);
    translations_main<<<grid, dim3(BLOCK), 0, stream>>>(tab, points, out, pairs_per_chunk, M);
}

// Round 4
// 70.797 us; speedup vs baseline: 1.0410x; 1.0268x over previous
//
#include <hip/hip_runtime.h>
#include <hip/hip_bf16.h>

#define BLOCK 256
#define MAXPAIRS 64         // n-pairs per chunk (chunk = 128 n-points)
#define LOG2E 1.44269504088896340736f

using v2f = __attribute__((ext_vector_type(2))) float;

// v(p_m) = sum_n exp(-|p_m - g_n|^2) * c_n   (SIGMA = 1)
// exp(-|p-g|^2) = exp(-|p|^2) * [exp(-|g|^2)] * exp2(2*log2e * p.g)
//
// R1-R3 post-mortem: inner-loop changes (LDS vs global loads, packed fp32) all
// landed at ~70-73 us total; per-SIMD VALU floor is only ~7 us, so the shared
// ~30 us was elsewhere. Prime suspect: 524K device-scope fp32 atomicAdds onto
// 2048 cache lines contended by 16 blocks across 8 non-coherent XCDs.
// R4: atomic-free two-stage reduction. Stage 1: grid (M/256, 32); each block
// preps its own 64-pair chunk table in LDS (folds exp(-|g|^2) and 2*log2e),
// then writes per-chunk partials to disjoint d_ws slabs with plain float2
// stores. Stage 2: sums the 32 partials per m. No memset, no prep kernel,
// no atomics. 8192 waves = 8/SIMD = max occupancy.

__global__ void __launch_bounds__(BLOCK)
stage1(const float* __restrict__ gd, const float* __restrict__ controls,
       const float* __restrict__ points, float2* __restrict__ partial,
       int Npairs, int M) {
    __shared__ float4 sg[2 * MAXPAIRS];   // [pair]: {gx0,gx1,gy0,gy1}, {c00,c01,c10,c11}

    const int tid = threadIdx.x;
    const int c   = blockIdx.y;

    // In-block prep of this chunk's folded table (zero-pad OOB pairs: B=0 -> contributes 0).
    if (tid < MAXPAIRS) {
        const int k = c * MAXPAIRS + tid;
        if (k < Npairs) {
            float2 g0 = ((const float2*)gd)[2 * k];
            float2 g1 = ((const float2*)gd)[2 * k + 1];
            float2 c0 = ((const float2*)controls)[2 * k];
            float2 c1 = ((const float2*)controls)[2 * k + 1];
            float  e0 = __expf(-(g0.x * g0.x + g0.y * g0.y));
            float  e1 = __expf(-(g1.x * g1.x + g1.y * g1.y));
            const float L2 = 2.0f * LOG2E;
            sg[2 * tid]     = make_float4(g0.x * L2, g1.x * L2, g0.y * L2, g1.y * L2);
            sg[2 * tid + 1] = make_float4(c0.x * e0, c1.x * e1, c0.y * e0, c1.y * e1);
        } else {
            sg[2 * tid]     = make_float4(0.f, 0.f, 0.f, 0.f);
            sg[2 * tid + 1] = make_float4(0.f, 0.f, 0.f, 0.f);
        }
    }
    __syncthreads();

    const int m = blockIdx.x * BLOCK + tid;
    if (m >= M) return;
    const float2 p = ((const float2*)points)[m];
    const v2f px = {p.x, p.x};
    const v2f py = {p.y, p.y};

    v2f acc0 = {0.f, 0.f};
    v2f acc1 = {0.f, 0.f};
#pragma unroll 8
    for (int k = 0; k < MAXPAIRS; ++k) {
        float4 A = sg[2 * k];                   // (gx0, gx1, gy0, gy1) * 2*log2e
        float4 B = sg[2 * k + 1];               // (c00, c01, c10, c11) * exp(-|g|^2)
        v2f gx = {A.x, A.y}, gy = {A.z, A.w};
        v2f c0 = {B.x, B.y}, c1 = {B.z, B.w};
        v2f d  = __builtin_elementwise_fma(gy, py, gx * px);
        v2f e  = { __builtin_amdgcn_exp2f(d.x),
                   __builtin_amdgcn_exp2f(d.y) };
        acc0 = __builtin_elementwise_fma(e, c0, acc0);
        acc1 = __builtin_elementwise_fma(e, c1, acc1);
    }

    const float s = __expf(-(p.x * p.x + p.y * p.y));
    partial[(size_t)c * M + m] = make_float2((acc0.x + acc0.y) * s,
                                             (acc1.x + acc1.y) * s);
}

__global__ void __launch_bounds__(BLOCK)
stage2(const float2* __restrict__ partial, float2* __restrict__ out,
       int M, int nchunks) {
    const int m = blockIdx.x * BLOCK + threadIdx.x;
    if (m >= M) return;
    float ax = 0.f, ay = 0.f;
#pragma unroll 8
    for (int c = 0; c < nchunks; ++c) {
        float2 t = partial[(size_t)c * M + m];
        ax += t.x;
        ay += t.y;
    }
    out[m] = make_float2(ax, ay);
}

extern "C" void kernel_launch(void* const* d_in, const int* in_sizes, int n_in,
                              void* d_out, int out_size, void* d_ws, size_t ws_size,
                              hipStream_t stream) {
    const float* gd       = (const float*)d_in[0];  // [N*2]
    const float* controls = (const float*)d_in[1];  // [N*2]
    const float* points   = (const float*)d_in[2];  // [M,2]
    float2* out     = (float2*)d_out;               // [M] float2
    float2* partial = (float2*)d_ws;                // [nchunks][M] float2 (4 MB @ nc=32)

    const int N = in_sizes[0] / 2;
    const int M = in_sizes[2] / 2;
    const int Npairs  = N / 2;                             // 2048
    const int nchunks = (Npairs + MAXPAIRS - 1) / MAXPAIRS; // 32

    dim3 grid1((M + BLOCK - 1) / BLOCK, nchunks);
    stage1<<<grid1, dim3(BLOCK), 0, stream>>>(gd, controls, points, partial, Npairs, M);

    dim3 grid2((M + BLOCK - 1) / BLOCK);
    stage2<<<grid2, dim3(BLOCK), 0, stream>>>(partial, out, M, nchunks);
}